// Round 1
// baseline (869.807 us; speedup 1.0000x reference)
//
#include <hip/hip_runtime.h>
#include <hip/hip_bf16.h>
#include <stdint.h>

// Problem constants (match reference): N=262144 rows, C=256 channels, K=256 codes.
#define CCH   256
#define KK    256
#define ROWS_PER_BLOCK 512   // rows per gather block; N % 512 == 0

// ---------------------------------------------------------------------------
// Pass 1: compress white_table int32 -> uint8 (values are codes in [0,256)).
// 16.7M elements; each thread packs one int4 -> uchar4.
// ---------------------------------------------------------------------------
__global__ __launch_bounds__(256) void compress_table_kernel(
    const int4* __restrict__ t, uchar4* __restrict__ o, int n4) {
  int i = blockIdx.x * 256 + threadIdx.x;
  if (i < n4) {
    int4 v = t[i];
    o[i] = make_uchar4((unsigned char)v.x, (unsigned char)v.y,
                       (unsigned char)v.z, (unsigned char)v.w);
  }
}

// ---------------------------------------------------------------------------
// Pass 2: fused double-gather.
//   g = blockIdx.x % 8 -> 32-channel group (XCD swizzle: consecutive blockIdx
//   round-robin across the 8 XCDs, so each XCD's 4MB L2 caches one 2MB u8
//   table slice).
//   Thread layout: q = tid%8 -> channel quad (4 consecutive channels via
//   int4/float4), rsub = tid/8 -> row stripe of 32.
//   Codebook slice (32ch x 256 f32 = 32KB) staged in LDS to keep the second
//   gather off the TCC path.
// ---------------------------------------------------------------------------
template <typename TabT>
__global__ __launch_bounds__(256) void gather_kernel(
    const int4* __restrict__ left, const int4* __restrict__ right,
    const TabT* __restrict__ tab, const float* __restrict__ cb,
    float4* __restrict__ out, int nrows) {
  __shared__ float cbs[32 * KK];  // 32 KB

  const int g     = blockIdx.x & 7;
  const int chunk = blockIdx.x >> 3;
  const int q     = threadIdx.x & 7;    // channel quad within group
  const int rsub  = threadIdx.x >> 3;   // 0..31

  // Stage this group's codebook slice into LDS (8192 floats = 2048 float4).
  {
    const float4* cbg = (const float4*)(cb + (size_t)(g * 32) * KK);
    float4* cbl = (float4*)cbs;
#pragma unroll
    for (int i = 0; i < 8; ++i) cbl[threadIdx.x + i * 256] = cbg[threadIdx.x + i * 256];
  }
  __syncthreads();

  const int cbase = g * 32 + q * 4;                 // first of 4 channels
  const TabT* t0 = tab + (size_t)cbase * (KK * KK); // this quad's table base
  const int vecoff = g * 8 + q;                     // int4 offset within a row (row = 64 int4)

  int row = chunk * ROWS_PER_BLOCK + rsub;
#pragma unroll 4
  for (int it = 0; it < ROWS_PER_BLOCK / 32; ++it, row += 32) {
    if (row >= nrows) break;
    size_t vi = (size_t)row * 64 + vecoff;
    int4 L = left[vi];
    int4 R = right[vi];

    unsigned c0 = (unsigned)t0[          (unsigned)(L.x * KK + R.x)];
    unsigned c1 = (unsigned)t0[ 65536u + (unsigned)(L.y * KK + R.y)];
    unsigned c2 = (unsigned)t0[131072u + (unsigned)(L.z * KK + R.z)];
    unsigned c3 = (unsigned)t0[196608u + (unsigned)(L.w * KK + R.w)];

    float4 o;
    o.x = cbs[(q * 4 + 0) * KK + c0];
    o.y = cbs[(q * 4 + 1) * KK + c1];
    o.z = cbs[(q * 4 + 2) * KK + c2];
    o.w = cbs[(q * 4 + 3) * KK + c3];
    out[vi] = o;
  }
}

extern "C" void kernel_launch(void* const* d_in, const int* in_sizes, int n_in,
                              void* d_out, int out_size, void* d_ws, size_t ws_size,
                              hipStream_t stream) {
  const int*   left  = (const int*)d_in[0];
  const int*   right = (const int*)d_in[1];
  const int*   wt    = (const int*)d_in[2];   // [C, K, K] int32
  const float* cb    = (const float*)d_in[3]; // [C, K] float32
  float* out = (float*)d_out;

  const int nrows = in_sizes[0] / CCH;        // 262144
  const int tab_elems = CCH * KK * KK;        // 16,777,216
  const int blocks = ((nrows + ROWS_PER_BLOCK - 1) / ROWS_PER_BLOCK) * 8;

  if (ws_size >= (size_t)tab_elems) {
    unsigned char* tab8 = (unsigned char*)d_ws;
    int n4 = tab_elems / 4;
    compress_table_kernel<<<n4 / 256, 256, 0, stream>>>(
        (const int4*)wt, (uchar4*)tab8, n4);
    gather_kernel<unsigned char><<<blocks, 256, 0, stream>>>(
        (const int4*)left, (const int4*)right, tab8, cb, (float4*)out, nrows);
  } else {
    // Fallback: gather directly from the int32 table (slower, always correct).
    gather_kernel<int><<<blocks, 256, 0, stream>>>(
        (const int4*)left, (const int4*)right, wt, cb, (float4*)out, nrows);
  }
}